// Round 16
// baseline (134.035 us; speedup 1.0000x reference)
//
#include <hip/hip_runtime.h>
#include <stdint.h>

#define K_SEL 512
#define NBOX 1536          // 3 * K_SEL
#define HBITS 13
#define HBINS 8192         // 13-bit monotone-key histogram
#define NSHARD 128         // candidate-counter shards per scale
#define SEG 128            // entries per shard segment
#define HBLK 96            // hist blocks (8/24/64 per scale)
#define ICAP 56            // max tracked boxes per image (avg ~24)

// scale params
#define M0 32448           // 64*13*13*3
#define M1 129792          // 64*26*26*3
#define M2 519168          // 64*52*52*3
#define M_TOT (M0+M1+M2)   // 681408

// ws byte offsets — slices/THR/BOX/SKEY/TOPK rewritten every launch; CNT zeroed
// by k_hist block 0 (separate dispatch before first use) -> poison-proof.
#define OFF_HSL  0u           // 96*8192*4 = 3145728
#define OFF_CNT  3145728u     // 3*128*4 = 1536 -> 3147264
#define OFF_THR  3147264u     // 32 -> 3147296
#define OFF_CAND 3147296u     // 3*128*128*8 = 393216 -> 3540512
#define OFF_BOX  3540512u     // 1536*7*4 = 43008 -> 3583520
#define OFF_SKEY 3583520u     // 1536*8 = 12288 -> 3595808
#define OFF_TOPK 3595808u     // 1536*8 = 12288 -> 3608096

typedef unsigned long long u64;
typedef uint32_t u32;
typedef uint16_t u16;

__device__ __forceinline__ float sigf(float x) { return 1.0f / (1.0f + expf(-x)); }

__device__ __forceinline__ u32 fmono(float f) {
    u32 u = __float_as_uint(f);
    return (u & 0x80000000u) ? ~u : (u | 0x80000000u);
}

// ---------------- kernel 1: 96-block LDS histogram (2 copies) -> private slices ----------------
// 4x the CU parallelism of the 24-block version; waves alternate between two
// LDS histogram copies to halve same-address atomic serialization (conf>=0.5
// values concentrate in ~16 bins). Copies merged at slice writeback.
__global__ __launch_bounds__(1024) void k_hist(const float* p0, const float* p1, const float* p2,
                                               uint8_t* ws) {
    __shared__ u32 lh[2 * HBINS];          // 64 KB
    int t = threadIdx.x;
    for (int i = t; i < 2 * HBINS; i += 1024) lh[i] = 0;
    if (blockIdx.x == 0 && t < 3 * NSHARD) ((u32*)(ws + OFF_CNT))[t] = 0;
    __syncthreads();
    int b = blockIdx.x, s, b0, nb;
    if (b < 8)       { s = 0; b0 = b;      nb = 8;  }
    else if (b < 32) { s = 1; b0 = b - 8;  nb = 24; }
    else             { s = 2; b0 = b - 32; nb = 64; }
    int M = (s == 0) ? M0 : (s == 1) ? M1 : M2;
    int H = (s == 0) ? 13 : (s == 1) ? 26 : 52;
    int HW = H * H;
    const float* p = (s == 0) ? p0 : (s == 1) ? p1 : p2;
    u32 cofs = ((u32)(t >> 6) & 1u) * HBINS;          // wave-parity copy select
    for (int o = b0 * 1024 + t; o < M; o += nb * 1024) {
        int n = o / (3 * HW); int rem = o - n * 3 * HW;
        int a = rem / HW;     int pix = rem - a * HW;
        float conf = sigf(p[(size_t)(n * 255 + a * 85) * HW + pix]);
        atomicAdd(&lh[cofs + (fmono(conf) >> (32 - HBITS))], 1u);
    }
    __syncthreads();
    u32* slice = (u32*)(ws + OFF_HSL) + (u32)b * HBINS;
    for (int i = t; i < HBINS; i += 1024) slice[i] = lh[i] + lh[HBINS + i];
}

// ---------------- kernel 2: sum slices + suffix scan -> threshold bin per scale ----------------
__global__ __launch_bounds__(1024) void k_scan(uint8_t* ws) {
    int s = blockIdx.x;
    int b0 = (s == 0) ? 0 : (s == 1) ? 8 : 32;
    int b1 = (s == 0) ? 8 : (s == 1) ? 32 : 96;
    __shared__ u32 sum[1024];
    int t = threadIdx.x;
    u32 bins[8];
#pragma unroll
    for (int k = 0; k < 8; ++k) bins[k] = 0;
    for (int b = b0; b < b1; ++b) {
        const uint4* sl = (const uint4*)((u32*)(ws + OFF_HSL) + (u32)b * HBINS + t * 8);
        uint4 x = sl[0], y = sl[1];
        bins[0] += x.x; bins[1] += x.y; bins[2] += x.z; bins[3] += x.w;
        bins[4] += y.x; bins[5] += y.y; bins[6] += y.z; bins[7] += y.w;
    }
    u32 acc = 0;
#pragma unroll
    for (int k = 0; k < 8; ++k) acc += bins[k];
    sum[t] = acc;
    __syncthreads();
    for (int off = 1; off < 1024; off <<= 1) {        // inclusive suffix scan
        u32 v = (t + off < 1024) ? sum[t + off] : 0;
        __syncthreads();
        sum[t] += v;
        __syncthreads();
    }
    u32 excl = (t < 1023) ? sum[t + 1] : 0;           // count in bins above my range
    u32 mine = sum[t] - excl;
    if (excl < K_SEL && excl + mine >= K_SEL) {
        u32 cum = excl; int thr = t * 8;
#pragma unroll
        for (int k = 7; k >= 0; --k) {
            cum += bins[k];
            if (cum >= K_SEL) { thr = t * 8 + k; break; }
        }
        ((u32*)(ws + OFF_THR))[s] = (u32)thr;
    }
}

// ---------------- kernel 3: compact candidates (plane-order coalesced, sharded counters) ----------------
__global__ __launch_bounds__(1024) void k_compact(const float* p0, const float* p1, const float* p2,
                                                  uint8_t* ws) {
    int t = blockIdx.x * 1024 + threadIdx.x;
    if (t >= M_TOT) return;
    int s, o, H;
    if (t < M0)            { s = 0; o = t;           H = 13; }
    else if (t < M0 + M1)  { s = 1; o = t - M0;      H = 26; }
    else                   { s = 2; o = t - M0 - M1; H = 52; }
    const float* p = (s == 0) ? p0 : (s == 1) ? p1 : p2;
    int HW = H * H;
    int n = o / (3 * HW); int rem = o - n * 3 * HW;
    int a = rem / HW;     int pix = rem - a * HW;
    float conf = sigf(p[(size_t)(n * 255 + a * 85) * HW + pix]);
    u32 cb = fmono(conf);
    if ((cb >> (32 - HBITS)) >= ((u32*)(ws + OFF_THR))[s]) {
        int c = n * (3 * HW) + pix * 3 + a;           // reference flat (n,h,w,a) index
        int idx = s * NSHARD + (blockIdx.x & (NSHARD - 1));
        u32 pos = atomicAdd(&((u32*)(ws + OFF_CNT))[idx], 1u);
        if (pos < SEG) {
            u64 key = ((u64)cb << 32) | (u32)(~(u32)c);   // ties: smaller c ranks higher
            ((u64*)(ws + OFF_CAND))[(u32)idx * SEG + pos] = key;
        }
    }
}

// ---------------- kernel 4: per-scale gather + LDS bitonic sort -> sorted top-512 keys ----------------
__global__ __launch_bounds__(1024) void k_sortsel(uint8_t* ws) {
    int s = blockIdx.x;
    __shared__ u64 a_[4096];               // 32 KB
    __shared__ u32 scnt[NSHARD], spre[NSHARD];
    int t = threadIdx.x;
    if (t < NSHARD) {
        u32 v = ((u32*)(ws + OFF_CNT))[s * NSHARD + t];
        scnt[t] = (v > SEG) ? SEG : v;
        spre[t] = scnt[t];
    }
    __syncthreads();
    for (int off = 1; off < NSHARD; off <<= 1) {       // inclusive Hillis-Steele
        u32 v = (t >= off && t < NSHARD) ? spre[t - off] : 0;
        __syncthreads();
        if (t < NSHARD) spre[t] += v;
        __syncthreads();
    }
    u32 total = spre[NSHARD - 1];
    if (total > 4096) total = 4096;
    int n2 = K_SEL;
    while (n2 < (int)total) n2 <<= 1;
    for (int i = t; i < n2; i += 1024) a_[i] = 0ull;
    __syncthreads();
    if (t < NSHARD) {                                   // thread t copies shard t
        u32 base = spre[t] - scnt[t];
        const u64* seg = (const u64*)(ws + OFF_CAND) + (u32)(s * NSHARD + t) * SEG;
        for (u32 i = 0; i < scnt[t]; ++i)
            if (base + i < 4096) a_[base + i] = seg[i];
    }
    __syncthreads();
    for (int k = 2; k <= n2; k <<= 1) {                 // bitonic, descending
        for (int j = k >> 1; j > 0; j >>= 1) {
            for (int i = t; i < n2; i += 1024) {
                int ixj = i ^ j;
                if (ixj > i) {
                    bool desc = ((i & k) == 0);
                    u64 x = a_[i], y = a_[ixj];
                    if (desc ? (x < y) : (x > y)) { a_[i] = y; a_[ixj] = x; }
                }
            }
            __syncthreads();
        }
    }
    u64* topk = (u64*)(ws + OFF_TOPK) + s * K_SEL;
    for (int r = t; r < K_SEL; r += 1024) topk[r] = a_[r];
}

// ---------------- kernel 5: decode top-512 boxes, 16 lanes per box ----------------
__global__ __launch_bounds__(1024) void k_decode(const float* p0, const float* p1, const float* p2,
                                                 const float* a0, const float* a1, const float* a2,
                                                 uint8_t* ws) {
    int t = blockIdx.x * 1024 + threadIdx.x;
    int g = t >> 4, l = t & 15;
    if (g >= NBOX) return;
    int s = g >> 9;
    int H = (s == 0) ? 13 : (s == 1) ? 26 : 52;
    float stride = (s == 0) ? 32.f : (s == 1) ? 16.f : 8.f;
    const float* p    = (s == 0) ? p0 : (s == 1) ? p1 : p2;
    const float* anch = (s == 0) ? a0 : (s == 1) ? a1 : a2;
    int HW = H * H, hw3 = HW * 3;
    u64 key = ((u64*)(ws + OFF_TOPK))[g];
    int c = (int)(~(u32)key);
    int n = c / hw3; int rem = c - n * hw3;
    int pix = rem / 3; int aa = rem - pix * 3;
    size_t base = (size_t)(n * 255 + aa * 85) * HW + pix;
    // lane l: classes l, l+16, ..., l+64 (ascending -> strict > keeps lowest in-lane)
    float best = -INFINITY; int bi = 0x7FFFFFFF;
#pragma unroll
    for (int m = 0; m < 5; ++m) {
        int k2 = l + m * 16;
        float vv = p[base + (size_t)(5 + k2) * HW];
        if (vv > best) { best = vv; bi = k2; }
    }
    float vload = (l < 5) ? p[base + (size_t)l * HW] : 0.f;
    // argmax reduce over 16 lanes: val >, tie -> lower class idx (first occurrence)
#pragma unroll
    for (int off = 8; off > 0; off >>= 1) {
        float ov = __shfl_down(best, off, 16);
        int oi = __shfl_down(bi, off, 16);
        if (ov > best || (ov == best && oi < bi)) { best = ov; bi = oi; }
    }
    float v0 = __shfl(vload, 0, 16);
    float v1 = __shfl(vload, 1, 16);
    float v2 = __shfl(vload, 2, 16);
    float v3 = __shfl(vload, 3, 16);
    float v4 = __shfl(vload, 4, 16);
    if (l == 0) {
        int h = pix / H, w = pix - h * H;
        float conf = sigf(v0);
        float cx = ((float)w + sigf(v1)) * stride;
        float cy = ((float)h + sigf(v2)) * stride;
        float bw = anch[aa * 2 + 0] * expf(v3);
        float bh = anch[aa * 2 + 1] * expf(v4);
        float* box = (float*)(ws + OFF_BOX) + g * 7;
        box[0] = (float)n; box[1] = conf; box[2] = cx; box[3] = cy;
        box[4] = bw; box[5] = bh; box[6] = (float)bi;
        u32 mono = (conf > 0.5f) ? fmono(conf) : fmono(-INFINITY);
        ((u64*)(ws + OFF_SKEY))[g] = ((u64)mono << 32) | (u32)(~(u32)g);  // ties: smaller pos first
    }
}

// ---------------- kernel 6: merge-rank + ballot image-rank + wave-parallel NMS + output ----------------
__global__ __launch_bounds__(1024) void k_tail(uint8_t* ws, float* out) {
    __shared__ u64 sk[NBOX];                                        // 12 KB (aliased by wvcnt later)
    __shared__ u16 srt[NBOX];
    __shared__ float gx1[NBOX], gy1[NBOX], gx2[NBOX], gy2[NBOX], gar[NBOX];
    __shared__ u32 meta[NBOX];                                      // img | cls<<8 | val<<16
    __shared__ uint8_t gkeep[NBOX];
    __shared__ u16 lists[64 * ICAP];
    __shared__ u32 icnt[64];
    u32* wvcnt = (u32*)sk;                                          // alias after merge-rank
    int t = threadIdx.x;
    u64* skey = (u64*)(ws + OFF_SKEY);
    for (int i = t; i < NBOX; i += 1024) sk[i] = skey[i];
    __syncthreads();
    // merge-rank: grank = r + count of strictly-greater keys in the other two lists
    for (int i = t; i < NBOX; i += 1024) {
        int s = i >> 9, r = i & 511;
        u64 K = sk[i];
        int g = r;
#pragma unroll
        for (int s2 = 0; s2 < 3; ++s2) {
            if (s2 == s) continue;
            const u64* seg = &sk[s2 << 9];
            int lo = 0, hi = 512;
            while (lo < hi) {                          // first idx with seg[idx] <= K
                int mid = (lo + hi) >> 1;
                if (seg[mid] > K) lo = mid + 1; else hi = mid;
            }
            g += lo;
        }
        srt[g] = (u16)i;
    }
    __syncthreads();                                   // sk dead; wvcnt aliases it
    const float* box = (const float*)(ws + OFF_BOX);
    for (int i = t; i < NBOX; i += 1024) {
        int pos = srt[i];
        float b0 = box[pos * 7 + 0], b1 = box[pos * 7 + 1], b2 = box[pos * 7 + 2];
        float b3 = box[pos * 7 + 3], b4 = box[pos * 7 + 4], b5 = box[pos * 7 + 5];
        float b6 = box[pos * 7 + 6];
        gx1[i] = b2 - b4 * 0.5f;  gy1[i] = b3 - b5 * 0.5f;
        gx2[i] = b2 + b4 * 0.5f;  gy2[i] = b3 + b5 * 0.5f;
        gar[i] = b4 * b5;
        meta[i] = (u32)(int)b0 | ((u32)(int)b6 << 8) | ((b1 > 0.5f) ? (1u << 16) : 0u);
        gkeep[i] = 0;
        wvcnt[i] = 0;
    }
    __syncthreads();
    // phase 1: per-(sorted-wave, image) counts via 6-ballot match-any
#pragma unroll
    for (int pass = 0; pass < 2; ++pass) {
        int ii = t + pass * 1024;
        u32 img = (ii < NBOX) ? (meta[ii] & 63u) : 0u;
        u64 mask = ~0ull;
#pragma unroll
        for (int b = 0; b < 6; ++b) {
            bool bit = (img >> b) & 1u;
            u64 bal = __ballot(bit);
            mask &= bit ? bal : ~bal;
        }
        if (ii < NBOX) {
            int lane = ii & 63;
            int wrank = __popcll(mask & ((1ull << lane) - 1ull));
            if (wrank == 0) wvcnt[(ii >> 6) * 64 + img] = (u32)__popcll(mask);
        }
    }
    __syncthreads();
    // phase 2: global in-image rank -> lists; icnt by first 64 threads
    if (t < 64) {
        u32 c = 0;
        for (int w = 0; w < 24; ++w) c += wvcnt[w * 64 + t];
        icnt[t] = c;
    }
#pragma unroll
    for (int pass = 0; pass < 2; ++pass) {
        int ii = t + pass * 1024;
        u32 img = (ii < NBOX) ? (meta[ii] & 63u) : 0u;
        u64 mask = ~0ull;
#pragma unroll
        for (int b = 0; b < 6; ++b) {
            bool bit = (img >> b) & 1u;
            u64 bal = __ballot(bit);
            mask &= bit ? bal : ~bal;
        }
        if (ii < NBOX) {
            int lane = ii & 63;
            int wvv = ii >> 6;
            int r = __popcll(mask & ((1ull << lane) - 1ull));
            for (int w = 0; w < wvv; ++w) r += (int)wvcnt[w * 64 + img];
            if (r < ICAP) lists[img * ICAP + r] = (u16)ii;
        }
    }
    __syncthreads();
    // phase 3: NMS — wave wv handles images 4*wv..4*wv+3; lane = box rank
    {
        int wv = t >> 6, lane = t & 63;
        for (int im = wv * 4; im < wv * 4 + 4; ++im) {
            int cnt = (int)icnt[im]; if (cnt > ICAP) cnt = ICAP;
            float x1 = 0, y1 = 0, x2 = 0, y2 = 0, ar = 0;
            u32 cl = 0; int u = -1; bool val = false;
            if (lane < cnt) {
                u = lists[im * ICAP + lane];
                x1 = gx1[u]; y1 = gy1[u]; x2 = gx2[u]; y2 = gy2[u]; ar = gar[u];
                u32 m = meta[u]; cl = (m >> 8) & 0xFFu; val = (m >> 16) & 1u;
            }
            u64 valmask = __ballot(val);
            u64 keptmask = 0;
            for (int a = 0; a < cnt; ++a) {
                float ax1 = __shfl(x1, a), ay1 = __shfl(y1, a);
                float ax2 = __shfl(x2, a), ay2 = __shfl(y2, a);
                float aar = __shfl(ar, a);
                u32 acl = (u32)__shfl((int)cl, a);
                float ix1 = fmaxf(x1, ax1), iy1 = fmaxf(y1, ay1);
                float ix2 = fminf(x2, ax2), iy2 = fminf(y2, ay2);
                float iw = fmaxf(ix2 - ix1, 0.f), ih = fmaxf(iy2 - iy1, 0.f);
                float inter = iw * ih;
                float iou = inter / (ar + aar - inter + 1e-9f);
                bool viol = (lane < a) && ((keptmask >> lane) & 1ull) &&
                            (cl == acl) && (iou > 0.1f);
                u64 bal = __ballot(viol);
                bool kept = ((valmask >> a) & 1ull) && (bal == 0ull);
                if (kept) keptmask |= (1ull << a);
            }
            if (lane < cnt) gkeep[u] = (uint8_t)((keptmask >> lane) & 1ull);
        }
    }
    __syncthreads();
    for (int i = t; i < NBOX; i += 1024) {
        float kf = gkeep[i] ? 1.f : 0.f;
        int pos = srt[i];
        for (int k = 0; k < 7; ++k) out[i * 7 + k] = box[pos * 7 + k] * kf;
        out[NBOX * 7 + i] = kf;
    }
}

extern "C" void kernel_launch(void* const* d_in, const int* in_sizes, int n_in,
                              void* d_out, int out_size, void* d_ws, size_t ws_size,
                              hipStream_t stream) {
    const float* p0 = (const float*)d_in[0];
    const float* p1 = (const float*)d_in[1];
    const float* p2 = (const float*)d_in[2];
    const float* a0 = (const float*)d_in[3];
    const float* a1 = (const float*)d_in[4];
    const float* a2 = (const float*)d_in[5];
    uint8_t* ws = (uint8_t*)d_ws;
    float* out = (float*)d_out;

    const int CB = (M_TOT + 1023) / 1024;  // 666

    k_hist   <<<HBLK, 1024, 0, stream>>>(p0, p1, p2, ws);
    k_scan   <<<3, 1024, 0, stream>>>(ws);
    k_compact<<<CB, 1024, 0, stream>>>(p0, p1, p2, ws);
    k_sortsel<<<3, 1024, 0, stream>>>(ws);
    k_decode <<<24, 1024, 0, stream>>>(p0, p1, p2, a0, a1, a2, ws);
    k_tail   <<<1, 1024, 0, stream>>>(ws, out);
}

// Round 17
// 114.479 us; speedup vs baseline: 1.1708x; 1.1708x over previous
//
#include <hip/hip_runtime.h>
#include <stdint.h>

#define K_SEL 512
#define NBOX 1536          // 3 * K_SEL
#define CAND_CAP 4096
#define HBITS 13
#define HBINS 8192         // 13-bit monotone-key histogram
#define NSHARD 128         // candidate-counter shards per scale
#define SEG 128            // entries per shard segment
#define HBLK 64            // hist blocks (8/16/40 per scale)
#define HB0 8
#define HB1 16
#define HB2 40
#define ICAP 56            // max tracked boxes per image (avg ~24)

// scale params
#define M0 32448           // 64*13*13*3
#define M1 129792          // 64*26*26*3
#define M2 519168          // 64*52*52*3
#define M_TOT (M0+M1+M2)   // 681408

// ws byte offsets (HIST..CNT contiguous so one memset zeroes both)
#define OFF_HIST 0u           // 3*8192*4 = 98304
#define OFF_CNT  98304u       // 3*128*4 = 1536 -> 99840
#define OFF_THR  99840u       // 32 -> 99872
#define OFF_CAND 99872u       // 3*128*128*8 = 393216 -> 493088
#define OFF_BOX  493088u      // 1536*7*4 = 43008 -> 536096
#define OFF_SKEY 536096u      // 1536*8 = 12288 -> 548384
#define OFF_TOPK 548384u      // 1536*8 = 12288 -> 560672
#define ZERO_BYTES 99840u     // HIST + CNT

typedef unsigned long long u64;
typedef uint32_t u32;
typedef uint16_t u16;

__device__ __forceinline__ float sigf(float x) { return 1.0f / (1.0f + expf(-x)); }

__device__ __forceinline__ u32 fmono(float f) {
    u32 u = __float_as_uint(f);
    return (u & 0x80000000u) ? ~u : (u | 0x80000000u);
}

// ---------------- kernel 1: per-block LDS histogram -> global atomic merge ----------------
__global__ __launch_bounds__(1024) void k_hist(const float* p0, const float* p1, const float* p2,
                                               uint8_t* ws) {
    __shared__ u32 lh[HBINS];
    for (int i = threadIdx.x; i < HBINS; i += 1024) lh[i] = 0;
    __syncthreads();
    int b = blockIdx.x, s, b0, nb;
    if (b < HB0)            { s = 0; b0 = b;             nb = HB0; }
    else if (b < HB0 + HB1) { s = 1; b0 = b - HB0;       nb = HB1; }
    else                    { s = 2; b0 = b - HB0 - HB1; nb = HB2; }
    int M = (s == 0) ? M0 : (s == 1) ? M1 : M2;
    int H = (s == 0) ? 13 : (s == 1) ? 26 : 52;
    int HW = H * H;
    const float* p = (s == 0) ? p0 : (s == 1) ? p1 : p2;
    for (int o = b0 * 1024 + threadIdx.x; o < M; o += nb * 1024) {
        int n = o / (3 * HW); int rem = o - n * 3 * HW;
        int a = rem / HW;     int pix = rem - a * HW;
        float conf = sigf(p[(size_t)(n * 255 + a * 85) * HW + pix]);
        atomicAdd(&lh[fmono(conf) >> (32 - HBITS)], 1u);
    }
    __syncthreads();
    u32* gh = (u32*)(ws + OFF_HIST) + s * HBINS;
    for (int i = threadIdx.x; i < HBINS; i += 1024) {
        u32 v = lh[i];
        if (v) atomicAdd(&gh[i], v);
    }
}

// ---------------- kernel 2: suffix scan of 8192 bins -> threshold bin per scale ----------------
__global__ __launch_bounds__(1024) void k_scan(uint8_t* ws) {
    int s = blockIdx.x;
    u32* hist = (u32*)(ws + OFF_HIST) + s * HBINS;
    __shared__ u32 sum[1024];
    int t = threadIdx.x;
    u32 bins[8];
    const uint4* hp = (const uint4*)(hist + t * 8);
    uint4 x = hp[0], y = hp[1];
    bins[0] = x.x; bins[1] = x.y; bins[2] = x.z; bins[3] = x.w;
    bins[4] = y.x; bins[5] = y.y; bins[6] = y.z; bins[7] = y.w;
    u32 acc = 0;
#pragma unroll
    for (int k = 0; k < 8; ++k) acc += bins[k];
    sum[t] = acc;
    __syncthreads();
    for (int off = 1; off < 1024; off <<= 1) {        // inclusive suffix scan
        u32 v = (t + off < 1024) ? sum[t + off] : 0;
        __syncthreads();
        sum[t] += v;
        __syncthreads();
    }
    u32 excl = (t < 1023) ? sum[t + 1] : 0;           // count in bins above my range
    u32 mine = sum[t] - excl;
    if (excl < K_SEL && excl + mine >= K_SEL) {
        u32 cum = excl; int thr = t * 8;
#pragma unroll
        for (int k = 7; k >= 0; --k) {
            cum += bins[k];
            if (cum >= K_SEL) { thr = t * 8 + k; break; }
        }
        ((u32*)(ws + OFF_THR))[s] = (u32)thr;
    }
}

// ---------------- kernel 3: compact candidates (plane-order coalesced, sharded counters) ----------------
__global__ __launch_bounds__(1024) void k_compact(const float* p0, const float* p1, const float* p2,
                                                  uint8_t* ws) {
    int t = blockIdx.x * 1024 + threadIdx.x;
    if (t >= M_TOT) return;
    int s, o, H;
    if (t < M0)            { s = 0; o = t;           H = 13; }
    else if (t < M0 + M1)  { s = 1; o = t - M0;      H = 26; }
    else                   { s = 2; o = t - M0 - M1; H = 52; }
    const float* p = (s == 0) ? p0 : (s == 1) ? p1 : p2;
    int HW = H * H;
    int n = o / (3 * HW); int rem = o - n * 3 * HW;
    int a = rem / HW;     int pix = rem - a * HW;
    float conf = sigf(p[(size_t)(n * 255 + a * 85) * HW + pix]);
    u32 cb = fmono(conf);
    if ((cb >> (32 - HBITS)) >= ((u32*)(ws + OFF_THR))[s]) {
        int c = n * (3 * HW) + pix * 3 + a;           // reference flat (n,h,w,a) index
        int idx = s * NSHARD + (blockIdx.x & (NSHARD - 1));
        u32 pos = atomicAdd(&((u32*)(ws + OFF_CNT))[idx], 1u);
        if (pos < SEG) {
            u64 key = ((u64)cb << 32) | (u32)(~(u32)c);   // ties: smaller c ranks higher
            ((u64*)(ws + OFF_CAND))[(u32)idx * SEG + pos] = key;
        }
    }
}

// ---------------- kernel 4: per-scale gather + LDS bitonic sort -> sorted top-512 keys ----------------
__global__ __launch_bounds__(1024) void k_sortsel(uint8_t* ws) {
    int s = blockIdx.x;
    __shared__ u64 a_[CAND_CAP];           // 32 KB
    __shared__ u32 scnt[NSHARD], spre[NSHARD];
    __shared__ u32 total_s;
    int t = threadIdx.x;
    if (t < NSHARD) {
        u32 v = ((u32*)(ws + OFF_CNT))[s * NSHARD + t];
        scnt[t] = (v > SEG) ? SEG : v;
        spre[t] = scnt[t];
    }
    __syncthreads();
    for (int off = 1; off < NSHARD; off <<= 1) {       // inclusive Hillis-Steele
        u32 v = (t >= off && t < NSHARD) ? spre[t - off] : 0;
        __syncthreads();
        if (t < NSHARD) spre[t] += v;
        __syncthreads();
    }
    if (t == 0) total_s = (spre[NSHARD - 1] > CAND_CAP) ? CAND_CAP : spre[NSHARD - 1];
    __syncthreads();
    u32 total = total_s;
    int n2 = K_SEL;
    while (n2 < (int)total) n2 <<= 1;
    for (int i = t; i < n2; i += 1024) a_[i] = 0ull;
    __syncthreads();
    if (t < NSHARD) {                                   // thread t copies shard t
        u32 base = spre[t] - scnt[t];
        const u64* seg = (const u64*)(ws + OFF_CAND) + (u32)(s * NSHARD + t) * SEG;
        for (u32 i = 0; i < scnt[t]; ++i)
            if (base + i < CAND_CAP) a_[base + i] = seg[i];
    }
    __syncthreads();
    for (int k = 2; k <= n2; k <<= 1) {                 // bitonic, descending
        for (int j = k >> 1; j > 0; j >>= 1) {
            for (int i = t; i < n2; i += 1024) {
                int ixj = i ^ j;
                if (ixj > i) {
                    bool desc = ((i & k) == 0);
                    u64 x = a_[i], y = a_[ixj];
                    if (desc ? (x < y) : (x > y)) { a_[i] = y; a_[ixj] = x; }
                }
            }
            __syncthreads();
        }
    }
    u64* topk = (u64*)(ws + OFF_TOPK) + s * K_SEL;
    for (int r = t; r < K_SEL; r += 1024) topk[r] = a_[r];
}

// ---------------- kernel 5: decode top-512 boxes, 16 lanes per box, 96 blocks x 256 ----------------
// SAME 24576 threads as the 24x1024 version, spread over 4x more CUs so the
// 1536x85 scattered cold-HBM gather gets 4x the outstanding-miss capacity.
__global__ __launch_bounds__(256) void k_decode(const float* p0, const float* p1, const float* p2,
                                                const float* a0, const float* a1, const float* a2,
                                                uint8_t* ws) {
    int t = blockIdx.x * 256 + threadIdx.x;
    int g = t >> 4, l = t & 15;
    if (g >= NBOX) return;
    int s = g >> 9;
    int H = (s == 0) ? 13 : (s == 1) ? 26 : 52;
    float stride = (s == 0) ? 32.f : (s == 1) ? 16.f : 8.f;
    const float* p    = (s == 0) ? p0 : (s == 1) ? p1 : p2;
    const float* anch = (s == 0) ? a0 : (s == 1) ? a1 : a2;
    int HW = H * H, hw3 = HW * 3;
    u64 key = ((u64*)(ws + OFF_TOPK))[g];
    int c = (int)(~(u32)key);
    int n = c / hw3; int rem = c - n * hw3;
    int pix = rem / 3; int aa = rem - pix * 3;
    size_t base = (size_t)(n * 255 + aa * 85) * HW + pix;
    // lane l: classes l, l+16, ..., l+64 (ascending -> strict > keeps lowest in-lane)
    float best = -INFINITY; int bi = 0x7FFFFFFF;
#pragma unroll
    for (int m = 0; m < 5; ++m) {
        int k2 = l + m * 16;
        float vv = p[base + (size_t)(5 + k2) * HW];
        if (vv > best) { best = vv; bi = k2; }
    }
    float vload = (l < 5) ? p[base + (size_t)l * HW] : 0.f;
    // argmax reduce over 16 lanes: val >, tie -> lower class idx (first occurrence)
#pragma unroll
    for (int off = 8; off > 0; off >>= 1) {
        float ov = __shfl_down(best, off, 16);
        int oi = __shfl_down(bi, off, 16);
        if (ov > best || (ov == best && oi < bi)) { best = ov; bi = oi; }
    }
    float v0 = __shfl(vload, 0, 16);
    float v1 = __shfl(vload, 1, 16);
    float v2 = __shfl(vload, 2, 16);
    float v3 = __shfl(vload, 3, 16);
    float v4 = __shfl(vload, 4, 16);
    if (l == 0) {
        int h = pix / H, w = pix - h * H;
        float conf = sigf(v0);
        float cx = ((float)w + sigf(v1)) * stride;
        float cy = ((float)h + sigf(v2)) * stride;
        float bw = anch[aa * 2 + 0] * expf(v3);
        float bh = anch[aa * 2 + 1] * expf(v4);
        float* box = (float*)(ws + OFF_BOX) + g * 7;
        box[0] = (float)n; box[1] = conf; box[2] = cx; box[3] = cy;
        box[4] = bw; box[5] = bh; box[6] = (float)bi;
        u32 mono = (conf > 0.5f) ? fmono(conf) : fmono(-INFINITY);
        ((u64*)(ws + OFF_SKEY))[g] = ((u64)mono << 32) | (u32)(~(u32)g);  // ties: smaller pos first
    }
}

// ---------------- kernel 6: merge-rank + ballot image-rank + wave-parallel NMS + output ----------------
__global__ __launch_bounds__(1024) void k_tail(uint8_t* ws, float* out) {
    __shared__ u64 sk[NBOX];                                        // 12 KB (aliased by wvcnt later)
    __shared__ u16 srt[NBOX];
    __shared__ float gx1[NBOX], gy1[NBOX], gx2[NBOX], gy2[NBOX], gar[NBOX];
    __shared__ u32 meta[NBOX];                                      // img | cls<<8 | val<<16
    __shared__ uint8_t gkeep[NBOX];
    __shared__ u16 lists[64 * ICAP];
    __shared__ u32 icnt[64];
    u32* wvcnt = (u32*)sk;                                          // alias after merge-rank
    int t = threadIdx.x;
    u64* skey = (u64*)(ws + OFF_SKEY);
    for (int i = t; i < NBOX; i += 1024) sk[i] = skey[i];
    __syncthreads();
    // merge-rank: grank = r + count of strictly-greater keys in the other two lists
    for (int i = t; i < NBOX; i += 1024) {
        int s = i >> 9, r = i & 511;
        u64 K = sk[i];
        int g = r;
#pragma unroll
        for (int s2 = 0; s2 < 3; ++s2) {
            if (s2 == s) continue;
            const u64* seg = &sk[s2 << 9];
            int lo = 0, hi = 512;
            while (lo < hi) {                          // first idx with seg[idx] <= K
                int mid = (lo + hi) >> 1;
                if (seg[mid] > K) lo = mid + 1; else hi = mid;
            }
            g += lo;
        }
        srt[g] = (u16)i;
    }
    __syncthreads();                                   // sk dead; wvcnt aliases it
    const float* box = (const float*)(ws + OFF_BOX);
    for (int i = t; i < NBOX; i += 1024) {
        int pos = srt[i];
        float b0 = box[pos * 7 + 0], b1 = box[pos * 7 + 1], b2 = box[pos * 7 + 2];
        float b3 = box[pos * 7 + 3], b4 = box[pos * 7 + 4], b5 = box[pos * 7 + 5];
        float b6 = box[pos * 7 + 6];
        gx1[i] = b2 - b4 * 0.5f;  gy1[i] = b3 - b5 * 0.5f;
        gx2[i] = b2 + b4 * 0.5f;  gy2[i] = b3 + b5 * 0.5f;
        gar[i] = b4 * b5;
        meta[i] = (u32)(int)b0 | ((u32)(int)b6 << 8) | ((b1 > 0.5f) ? (1u << 16) : 0u);
        gkeep[i] = 0;
        wvcnt[i] = 0;
    }
    __syncthreads();
    // phase 1: per-(sorted-wave, image) counts via 6-ballot match-any
#pragma unroll
    for (int pass = 0; pass < 2; ++pass) {
        int ii = t + pass * 1024;
        u32 img = (ii < NBOX) ? (meta[ii] & 63u) : 0u;
        u64 mask = ~0ull;
#pragma unroll
        for (int b = 0; b < 6; ++b) {
            bool bit = (img >> b) & 1u;
            u64 bal = __ballot(bit);
            mask &= bit ? bal : ~bal;
        }
        if (ii < NBOX) {
            int lane = ii & 63;
            int wrank = __popcll(mask & ((1ull << lane) - 1ull));
            if (wrank == 0) wvcnt[(ii >> 6) * 64 + img] = (u32)__popcll(mask);
        }
    }
    __syncthreads();
    // phase 2: global in-image rank -> lists; icnt by first 64 threads
    if (t < 64) {
        u32 c = 0;
        for (int w = 0; w < 24; ++w) c += wvcnt[w * 64 + t];
        icnt[t] = c;
    }
#pragma unroll
    for (int pass = 0; pass < 2; ++pass) {
        int ii = t + pass * 1024;
        u32 img = (ii < NBOX) ? (meta[ii] & 63u) : 0u;
        u64 mask = ~0ull;
#pragma unroll
        for (int b = 0; b < 6; ++b) {
            bool bit = (img >> b) & 1u;
            u64 bal = __ballot(bit);
            mask &= bit ? bal : ~bal;
        }
        if (ii < NBOX) {
            int lane = ii & 63;
            int wvv = ii >> 6;
            int r = __popcll(mask & ((1ull << lane) - 1ull));
            for (int w = 0; w < wvv; ++w) r += (int)wvcnt[w * 64 + img];
            if (r < ICAP) lists[img * ICAP + r] = (u16)ii;
        }
    }
    __syncthreads();
    // phase 3: NMS — wave wv handles images 4*wv..4*wv+3; lane = box rank
    {
        int wv = t >> 6, lane = t & 63;
        for (int im = wv * 4; im < wv * 4 + 4; ++im) {
            int cnt = (int)icnt[im]; if (cnt > ICAP) cnt = ICAP;
            float x1 = 0, y1 = 0, x2 = 0, y2 = 0, ar = 0;
            u32 cl = 0; int u = -1; bool val = false;
            if (lane < cnt) {
                u = lists[im * ICAP + lane];
                x1 = gx1[u]; y1 = gy1[u]; x2 = gx2[u]; y2 = gy2[u]; ar = gar[u];
                u32 m = meta[u]; cl = (m >> 8) & 0xFFu; val = (m >> 16) & 1u;
            }
            u64 valmask = __ballot(val);
            u64 keptmask = 0;
            for (int a = 0; a < cnt; ++a) {
                float ax1 = __shfl(x1, a), ay1 = __shfl(y1, a);
                float ax2 = __shfl(x2, a), ay2 = __shfl(y2, a);
                float aar = __shfl(ar, a);
                u32 acl = (u32)__shfl((int)cl, a);
                float ix1 = fmaxf(x1, ax1), iy1 = fmaxf(y1, ay1);
                float ix2 = fminf(x2, ax2), iy2 = fminf(y2, ay2);
                float iw = fmaxf(ix2 - ix1, 0.f), ih = fmaxf(iy2 - iy1, 0.f);
                float inter = iw * ih;
                float iou = inter / (ar + aar - inter + 1e-9f);
                bool viol = (lane < a) && ((keptmask >> lane) & 1ull) &&
                            (cl == acl) && (iou > 0.1f);
                u64 bal = __ballot(viol);
                bool kept = ((valmask >> a) & 1ull) && (bal == 0ull);
                if (kept) keptmask |= (1ull << a);
            }
            if (lane < cnt) gkeep[u] = (uint8_t)((keptmask >> lane) & 1ull);
        }
    }
    __syncthreads();
    for (int i = t; i < NBOX; i += 1024) {
        float kf = gkeep[i] ? 1.f : 0.f;
        int pos = srt[i];
        for (int k = 0; k < 7; ++k) out[i * 7 + k] = box[pos * 7 + k] * kf;
        out[NBOX * 7 + i] = kf;
    }
}

extern "C" void kernel_launch(void* const* d_in, const int* in_sizes, int n_in,
                              void* d_out, int out_size, void* d_ws, size_t ws_size,
                              hipStream_t stream) {
    const float* p0 = (const float*)d_in[0];
    const float* p1 = (const float*)d_in[1];
    const float* p2 = (const float*)d_in[2];
    const float* a0 = (const float*)d_in[3];
    const float* a1 = (const float*)d_in[4];
    const float* a2 = (const float*)d_in[5];
    uint8_t* ws = (uint8_t*)d_ws;
    float* out = (float*)d_out;

    const int CB = (M_TOT + 1023) / 1024;  // 666

    hipMemsetAsync(ws, 0, ZERO_BYTES, stream);   // hist + cnt
    k_hist   <<<HBLK, 1024, 0, stream>>>(p0, p1, p2, ws);
    k_scan   <<<3, 1024, 0, stream>>>(ws);
    k_compact<<<CB, 1024, 0, stream>>>(p0, p1, p2, ws);
    k_sortsel<<<3, 1024, 0, stream>>>(ws);
    k_decode <<<96, 256, 0, stream>>>(p0, p1, p2, a0, a1, a2, ws);
    k_tail   <<<1, 1024, 0, stream>>>(ws, out);
}